// Round 3
// baseline (516.064 us; speedup 1.0000x reference)
//
#include <hip/hip_runtime.h>

namespace {

typedef float vf4 __attribute__((ext_vector_type(4)));

// cos(2*pi*n/64); sin(2*pi*n/64) = COS64[(n+48)&63]
constexpr float COS64[64] = {
  1.00000000f,  0.99518473f,  0.98078528f,  0.95694034f,
  0.92387953f,  0.88192126f,  0.83146961f,  0.77301045f,
  0.70710678f,  0.63439328f,  0.55557023f,  0.47139674f,
  0.38268343f,  0.29028468f,  0.19509032f,  0.09801714f,
  0.00000000f, -0.09801714f, -0.19509032f, -0.29028468f,
 -0.38268343f, -0.47139674f, -0.55557023f, -0.63439328f,
 -0.70710678f, -0.77301045f, -0.83146961f, -0.88192126f,
 -0.92387953f, -0.95694034f, -0.98078528f, -0.99518473f,
 -1.00000000f, -0.99518473f, -0.98078528f, -0.95694034f,
 -0.92387953f, -0.88192126f, -0.83146961f, -0.77301045f,
 -0.70710678f, -0.63439328f, -0.55557023f, -0.47139674f,
 -0.38268343f, -0.29028468f, -0.19509032f, -0.09801714f,
 -0.00000000f,  0.09801714f,  0.19509032f,  0.29028468f,
  0.38268343f,  0.47139674f,  0.55557023f,  0.63439328f,
  0.70710678f,  0.77301045f,  0.83146961f,  0.88192126f,
  0.92387953f,  0.95694034f,  0.98078528f,  0.99518473f };

// cos(2*pi*n/16); sin(2*pi*n/16) = C16[(n+12)&15]
constexpr float C16[16] = {
  1.00000000f,  0.92387953f,  0.70710678f,  0.38268343f,
  0.00000000f, -0.38268343f, -0.70710678f, -0.92387953f,
 -1.00000000f, -0.92387953f, -0.70710678f, -0.38268343f,
 -0.00000000f,  0.38268343f,  0.70710678f,  0.92387953f };

constexpr float TWOPI_64 = 0.09817477042468103f; // 2*pi/64
constexpr int MM = 144;   // 16 ky * 9 kz
constexpr int GD = 2304;  // 16 kx * 144
constexpr int ZW = 576;   // 9 kz * 64 w  (per-slice z-DFT output)

// ---------------------------------------------------------------------------
// K1: pure streaming z-DFT. x[slice][w][d] -> buf1[slice][kz*64 + w] complex.
// No LDS, no barrier: 4-lane shuffle reduce, q==0 lanes store.
// ---------------------------------------------------------------------------
__global__ __launch_bounds__(256) void k1_fwd(const float* __restrict__ x,
                                              float2* __restrict__ buf1) {
  const int tid = threadIdx.x;
  const int slice = blockIdx.x;        // bc*64 + h
  const int w = tid >> 2, q = tid & 3;

  const float4* xp = (const float4*)(x + ((size_t)slice << 12));
  float4 a0 = xp[tid * 4 + 0];
  float4 a1 = xp[tid * 4 + 1];
  float4 a2 = xp[tid * 4 + 2];
  float4 a3 = xp[tid * 4 + 3];
  float xv[16] = {a0.x, a0.y, a0.z, a0.w, a1.x, a1.y, a1.z, a1.w,
                  a2.x, a2.y, a2.z, a2.w, a3.x, a3.y, a3.z, a3.w};

  // partial z-DFT with compile-time twiddles: sum_j xv[j] e^{-2pi i kz j/64}
  float ar[9], ai[9];
#pragma unroll
  for (int kz = 0; kz < 9; ++kz) { ar[kz] = 0.f; ai[kz] = 0.f; }
#pragma unroll
  for (int j = 0; j < 16; ++j) {
    const float v = xv[j];
#pragma unroll
    for (int kz = 0; kz < 9; ++kz) {
      const int n = (kz * j) & 63;
      ar[kz] = fmaf(v, COS64[n], ar[kz]);
      ai[kz] = fmaf(v, -COS64[(n + 48) & 63], ai[kz]);
    }
  }
  // rotate by (-i)^{(q*kz)&3} (the e^{-2pi i kz 16q/64} factor), reduce over q
  float2* bp = buf1 + (size_t)slice * ZW;
#pragma unroll
  for (int kz = 0; kz < 9; ++kz) {
    const int m = (q * kz) & 3;
    const float a = ar[kz], b = ai[kz];
    float r  = (m & 1) ? b : a;
    float i2 = (m & 1) ? a : b;
    r  = (m >= 2) ? -r : r;
    i2 = (m == 1 || m == 2) ? -i2 : i2;
    r  += __shfl_xor(r, 1);  r  += __shfl_xor(r, 2);
    i2 += __shfl_xor(i2, 1); i2 += __shfl_xor(i2, 2);
    if (q == 0) bp[kz * 64 + w] = make_float2(r, i2);
  }
}

// ---------------------------------------------------------------------------
// K2: per (bc, kz): w-DFT (64->16 ky) then h-DFT (64->16 kx).
// grid (9, 256). LDS: As[h][w] XOR-swizzled on w; Bs[h][ky] stride 17.
// ---------------------------------------------------------------------------
__global__ __launch_bounds__(256) void k2_fwd(const float2* __restrict__ buf1,
                                              float2* __restrict__ buf2) {
  __shared__ float2 As[64 * 64];       // idx = h*64 + (w ^ (h&31))
  __shared__ float2 Bs[64 * 17];       // idx = h*17 + ky
  const int tid = threadIdx.x;
  const int kz = blockIdx.x, bc = blockIdx.y;

  // load: thread holds w = tid&63 fixed, h = (tid>>6)+4i
  {
    const int wl = tid & 63, hb = tid >> 6;
#pragma unroll
    for (int i = 0; i < 16; ++i) {
      const int h = hb + 4 * i;
      As[h * 64 + (wl ^ (h & 31))] =
          buf1[((size_t)bc * 64 + h) * ZW + kz * 64 + wl];
    }
  }
  __syncthreads();

  // w-DFT: thread (h = tid&63, kyg = tid>>6) computes ky = kyg+4j, j=0..3
  const int h = tid & 63, kyg = tid >> 6;
  float bR[4] = {0.f, 0.f, 0.f, 0.f}, bI[4] = {0.f, 0.f, 0.f, 0.f};
  {
    const float sc = COS64[kyg];              // step = e^{-2pi i kyg/64}
    const float ss = COS64[(kyg + 48) & 63];  // sin
    float pR = 1.f, pI = 0.f;
    const int hl = h & 31;
    const float2* Ah = As + h * 64;
    for (int w1 = 0; w1 < 4; ++w1) {
#pragma unroll
      for (int w0 = 0; w0 < 16; ++w0) {
        const int w = w1 * 16 + w0;
        const float2 a = Ah[w ^ hl];
        const float tR = a.x * pR - a.y * pI;
        const float tI = a.x * pI + a.y * pR;
        bR[0] += tR; bI[0] += tI;
#pragma unroll
        for (int j = 1; j < 4; ++j) {
          const int n = (j * w0) & 15;
          const float c = C16[n], s = C16[(n + 12) & 15];
          bR[j] = fmaf(tR, c, fmaf(tI, s, bR[j]));
          bI[j] = fmaf(tI, c, fmaf(-tR, s, bI[j]));
        }
        const float nR = fmaf(pR, sc, pI * ss);
        const float nI = fmaf(pI, sc, -pR * ss);
        pR = nR; pI = nI;
      }
    }
  }
#pragma unroll
  for (int j = 0; j < 4; ++j)
    Bs[h * 17 + kyg + 4 * j] = make_float2(bR[j], bI[j]);
  __syncthreads();

  // h-DFT: thread (kx = tid>>4, ky = tid&15)
  {
    const int kx = tid >> 4, ky = tid & 15;
    const float hc = COS64[kx];               // step = e^{-2pi i kx/64}
    const float hs = COS64[(kx + 48) & 63];
    float qR = 1.f, qI = 0.f, sR = 0.f, sI = 0.f;
    for (int h2 = 0; h2 < 64; ++h2) {
      const float2 b = Bs[h2 * 17 + ky];
      sR = fmaf(b.x, qR, fmaf(-b.y, qI, sR));
      sI = fmaf(b.x, qI, fmaf( b.y, qR, sI));
      const float nR = fmaf(qR, hc, qI * hs);
      const float nI = fmaf(qI, hc, -qR * hs);
      qR = nR; qI = nI;
    }
    buf2[(size_t)bc * GD + kx * MM + ky * 9 + kz] = make_float2(sR, sI);
  }
}

// ---------------------------------------------------------------------------
// K3: gate MLP. pooled[b][c] = S_DC.re / 64^3. Writes g-1.
// ---------------------------------------------------------------------------
__global__ __launch_bounds__(256) void k3_gates(const float2* __restrict__ buf2,
    const float* __restrict__ w1, const float* __restrict__ b1,
    const float* __restrict__ w2, const float* __restrict__ b2,
    float* __restrict__ gm1) {
  __shared__ float pooled[64];
  __shared__ float hs[16];
  const int b = blockIdx.x, tid = threadIdx.x;
  if (tid < 64)
    pooled[tid] = buf2[(size_t)(b * 64 + tid) * GD].x * (1.f / 262144.f);
  __syncthreads();
  if (tid < 16) {
    float acc = b1[tid];
    for (int c = 0; c < 64; ++c) acc = fmaf(pooled[c], w1[c * 16 + tid], acc);
    hs[tid] = fmaxf(acc, 0.f);
  }
  __syncthreads();
#pragma unroll
  for (int r = 0; r < 9; ++r) {
    const int o = tid + r * 256;
    float acc = b2[o];
#pragma unroll
    for (int j = 0; j < 16; ++j) acc = fmaf(hs[j], w2[j * GD + o], acc);
    gm1[b * GD + o] = 1.f / (1.f + expf(-acc)) - 1.f;
  }
}

// ---------------------------------------------------------------------------
// K4b: inverse synthesis per slice, gate fused in phase 1;
//      out = x + delta/64^3 (nontemporal stores)
// ---------------------------------------------------------------------------
__global__ __launch_bounds__(256) void k4b_final(const float2* __restrict__ S,
                                                 const float* __restrict__ gm1,
                                                 const float* __restrict__ x,
                                                 float* __restrict__ out) {
  __shared__ float2 C1s[MM];
  __shared__ float2 C2s[9 * 65];       // C2[kz][w], padded
  const int tid = threadIdx.x, slice = blockIdx.x;
  const int bc = slice >> 6, h = slice & 63, b = bc >> 6;

  // C1[m] = sum_kx (g-1)*S[bc][kx][m] e^{+2pi i kx h/64}
  if (tid < MM) {
    const float2* Sp = S + (size_t)bc * GD + tid;
    const float* Gp = gm1 + (size_t)b * GD + tid;
    float sn, cs;
    sincosf(TWOPI_64 * (float)h, &sn, &cs);   // step = e^{+2pi i h/64}
    float px = 1.f, py = 0.f, ar = 0.f, ai = 0.f;
#pragma unroll
    for (int kx = 0; kx < 16; ++kx) {
      const float2 sv = Sp[kx * MM];
      const float g = Gp[kx * MM];
      const float dR = sv.x * g, dI = sv.y * g;
      ar = fmaf(dR, px, fmaf(-dI, py, ar));
      ai = fmaf(dR, py, fmaf( dI, px, ai));
      const float nx = fmaf(px, cs, -py * sn);
      const float ny = fmaf(px, sn,  py * cs);
      px = nx; py = ny;
    }
    C1s[tid] = make_float2(ar, ai);
  }
  __syncthreads();

  // C2[kz][w] = sum_ky C1[ky*9+kz] e^{+2pi i ky w/64}; thread (w,q) does kz set
  {
    const int w = tid >> 2, q = tid & 3;
    float sn, cs;
    sincosf(TWOPI_64 * (float)w, &sn, &cs);   // step = e^{+2pi i w/64}
    const int kz0 = q, kz1 = q + 4;           // q==0 also does kz=8
    float a0r = 0.f, a0i = 0.f, a1r = 0.f, a1i = 0.f, a2r = 0.f, a2i = 0.f;
    float px = 1.f, py = 0.f;
    for (int ky = 0; ky < 16; ++ky) {
      const float2 c0 = C1s[ky * 9 + kz0];
      const float2 c1 = C1s[ky * 9 + kz1];
      a0r = fmaf(c0.x, px, fmaf(-c0.y, py, a0r));
      a0i = fmaf(c0.x, py, fmaf( c0.y, px, a0i));
      a1r = fmaf(c1.x, px, fmaf(-c1.y, py, a1r));
      a1i = fmaf(c1.x, py, fmaf( c1.y, px, a1i));
      if (q == 0) {
        const float2 c2v = C1s[ky * 9 + 8];
        a2r = fmaf(c2v.x, px, fmaf(-c2v.y, py, a2r));
        a2i = fmaf(c2v.x, py, fmaf( c2v.y, px, a2i));
      }
      const float nx = fmaf(px, cs, -py * sn);
      const float ny = fmaf(px, sn,  py * cs);
      px = nx; py = ny;
    }
    C2s[kz0 * 65 + w] = make_float2(a0r, a0i);
    C2s[kz1 * 65 + w] = make_float2(a1r, a1i);
    if (q == 0) C2s[8 * 65 + w] = make_float2(a2r, a2i);
  }
  __syncthreads();

  // delta[w][d] = Re(C2[0]) + 2*sum_{kz>=1} Re(C2[kz] e^{+2pi i kz d/64});
  // d = 16q + j: e^{+2pi i kz d/64} = i^{kz q} * e^{+2pi i kz j/64}
  {
    const int w = tid >> 2, q = tid & 3;
    float cr[9], ci[9];
#pragma unroll
    for (int kz = 0; kz < 9; ++kz) {
      const float2 v = C2s[kz * 65 + w];
      const int m = (kz * q) & 3;                 // multiply by i^m
      const float a = v.x, b2_ = v.y;
      float r  = (m & 1) ? b2_ : a;
      float i2 = (m & 1) ? a : b2_;
      r  = (m == 1 || m == 2) ? -r : r;
      i2 = (m >= 2) ? -i2 : i2;
      cr[kz] = r; ci[kz] = i2;
    }
    float acc[16];
#pragma unroll
    for (int j = 0; j < 16; ++j) acc[j] = cr[0];
#pragma unroll
    for (int kz = 1; kz < 9; ++kz) {
#pragma unroll
      for (int j = 0; j < 16; ++j) {
        const int n = (kz * j) & 63;
        acc[j] = fmaf(cr[kz],  2.f * COS64[n], acc[j]);
        acc[j] = fmaf(ci[kz], -2.f * COS64[(n + 48) & 63], acc[j]);
      }
    }
    const float4* xp = (const float4*)(x + ((size_t)slice << 12) + w * 64 + q * 16);
    vf4* op = (vf4*)(out + ((size_t)slice << 12) + w * 64 + q * 16);
    const float scale = 1.f / 262144.f;
#pragma unroll
    for (int k = 0; k < 4; ++k) {
      float4 v = xp[k];
      vf4 o;
      o.x = v.x + acc[k * 4 + 0] * scale;
      o.y = v.y + acc[k * 4 + 1] * scale;
      o.z = v.z + acc[k * 4 + 2] * scale;
      o.w = v.w + acc[k * 4 + 3] * scale;
      __builtin_nontemporal_store(o, &op[k]);
    }
  }
}

} // namespace

extern "C" void kernel_launch(void* const* d_in, const int* in_sizes, int n_in,
                              void* d_out, int out_size, void* d_ws, size_t ws_size,
                              hipStream_t stream) {
  (void)in_sizes; (void)n_in; (void)out_size; (void)ws_size;
  const float* x  = (const float*)d_in[0];
  const float* w1 = (const float*)d_in[1];
  const float* b1 = (const float*)d_in[2];
  const float* w2 = (const float*)d_in[3];
  const float* b2 = (const float*)d_in[4];
  float* out = (float*)d_out;

  char* ws = (char*)d_ws;
  float2* buf1 = (float2*)ws;                          // 16384*576*8 = 75,497,472 B
  float2* buf2 = (float2*)(ws + 75497472);             // 256*2304*8  =  4,718,592 B
  float*  gm1  = (float*)(ws + 75497472 + 4718592);    // 4*2304*4    =     36,864 B

  hipLaunchKernelGGL(k1_fwd,   dim3(16384),    dim3(256), 0, stream, x, buf1);
  hipLaunchKernelGGL(k2_fwd,   dim3(9, 256),   dim3(256), 0, stream, buf1, buf2);
  hipLaunchKernelGGL(k3_gates, dim3(4),        dim3(256), 0, stream, buf2, w1, b1, w2, b2, gm1);
  hipLaunchKernelGGL(k4b_final,dim3(16384),    dim3(256), 0, stream, buf2, gm1, x, out);
}

// Round 4
// 274.345 us; speedup vs baseline: 1.8811x; 1.8811x over previous
//
#include <hip/hip_runtime.h>

namespace {

// cos(2*pi*n/64); sin(2*pi*n/64) = COS64[(n+48)&63]
constexpr float COS64[64] = {
  1.00000000f,  0.99518473f,  0.98078528f,  0.95694034f,
  0.92387953f,  0.88192126f,  0.83146961f,  0.77301045f,
  0.70710678f,  0.63439328f,  0.55557023f,  0.47139674f,
  0.38268343f,  0.29028468f,  0.19509032f,  0.09801714f,
  0.00000000f, -0.09801714f, -0.19509032f, -0.29028468f,
 -0.38268343f, -0.47139674f, -0.55557023f, -0.63439328f,
 -0.70710678f, -0.77301045f, -0.83146961f, -0.88192126f,
 -0.92387953f, -0.95694034f, -0.98078528f, -0.99518473f,
 -1.00000000f, -0.99518473f, -0.98078528f, -0.95694034f,
 -0.92387953f, -0.88192126f, -0.83146961f, -0.77301045f,
 -0.70710678f, -0.63439328f, -0.55557023f, -0.47139674f,
 -0.38268343f, -0.29028468f, -0.19509032f, -0.09801714f,
 -0.00000000f,  0.09801714f,  0.19509032f,  0.29028468f,
  0.38268343f,  0.47139674f,  0.55557023f,  0.63439328f,
  0.70710678f,  0.77301045f,  0.83146961f,  0.88192126f,
  0.92387953f,  0.95694034f,  0.98078528f,  0.99518473f };

// cos(2*pi*n/16); sin(2*pi*n/16) = C16[(n+12)&15]
constexpr float C16[16] = {
  1.00000000f,  0.92387953f,  0.70710678f,  0.38268343f,
  0.00000000f, -0.38268343f, -0.70710678f, -0.92387953f,
 -1.00000000f, -0.92387953f, -0.70710678f, -0.38268343f,
 -0.00000000f,  0.38268343f,  0.70710678f,  0.92387953f };

constexpr float TWOPI_64 = 0.09817477042468103f; // 2*pi/64
constexpr int MM = 144;   // 16 ky * 9 kz
constexpr int GD = 2304;  // 16 kx * 144
constexpr int ZW = 576;   // 9 kz * 64 w  (per-slice z-DFT output)

// ---------------------------------------------------------------------------
// K1: pure streaming z-DFT. x[slice][w][d] -> buf1[slice][kz*64 + w] complex.
// No LDS, no barrier: 4-lane shuffle reduce, q==0 lanes store.
// ---------------------------------------------------------------------------
__global__ __launch_bounds__(256) void k1_fwd(const float* __restrict__ x,
                                              float2* __restrict__ buf1) {
  const int tid = threadIdx.x;
  const int slice = blockIdx.x;        // bc*64 + h
  const int w = tid >> 2, q = tid & 3;

  const float4* xp = (const float4*)(x + ((size_t)slice << 12));
  float4 a0 = xp[tid * 4 + 0];
  float4 a1 = xp[tid * 4 + 1];
  float4 a2 = xp[tid * 4 + 2];
  float4 a3 = xp[tid * 4 + 3];
  float xv[16] = {a0.x, a0.y, a0.z, a0.w, a1.x, a1.y, a1.z, a1.w,
                  a2.x, a2.y, a2.z, a2.w, a3.x, a3.y, a3.z, a3.w};

  // partial z-DFT with compile-time twiddles: sum_j xv[j] e^{-2pi i kz j/64}
  float ar[9], ai[9];
#pragma unroll
  for (int kz = 0; kz < 9; ++kz) { ar[kz] = 0.f; ai[kz] = 0.f; }
#pragma unroll
  for (int j = 0; j < 16; ++j) {
    const float v = xv[j];
#pragma unroll
    for (int kz = 0; kz < 9; ++kz) {
      const int n = (kz * j) & 63;
      ar[kz] = fmaf(v, COS64[n], ar[kz]);
      ai[kz] = fmaf(v, -COS64[(n + 48) & 63], ai[kz]);
    }
  }
  // rotate by (-i)^{(q*kz)&3} (the e^{-2pi i kz 16q/64} factor), reduce over q
  float2* bp = buf1 + (size_t)slice * ZW;
#pragma unroll
  for (int kz = 0; kz < 9; ++kz) {
    const int m = (q * kz) & 3;
    const float a = ar[kz], b = ai[kz];
    float r  = (m & 1) ? b : a;
    float i2 = (m & 1) ? a : b;
    r  = (m >= 2) ? -r : r;
    i2 = (m == 1 || m == 2) ? -i2 : i2;
    r  += __shfl_xor(r, 1);  r  += __shfl_xor(r, 2);
    i2 += __shfl_xor(i2, 1); i2 += __shfl_xor(i2, 2);
    if (q == 0) bp[kz * 64 + w] = make_float2(r, i2);
  }
}

// ---------------------------------------------------------------------------
// K2: per (bc, kz): w-DFT (64->16 ky) then h-DFT (64->16 kx).
// grid (9, 256). LDS: As[h][w] XOR-swizzled on w; Bs[h][ky] stride 17.
// ---------------------------------------------------------------------------
__global__ __launch_bounds__(256) void k2_fwd(const float2* __restrict__ buf1,
                                              float2* __restrict__ buf2) {
  __shared__ float2 As[64 * 64];       // idx = h*64 + (w ^ (h&31))
  __shared__ float2 Bs[64 * 17];       // idx = h*17 + ky
  const int tid = threadIdx.x;
  const int kz = blockIdx.x, bc = blockIdx.y;

  // load: thread holds w = tid&63 fixed, h = (tid>>6)+4i
  {
    const int wl = tid & 63, hb = tid >> 6;
#pragma unroll
    for (int i = 0; i < 16; ++i) {
      const int h = hb + 4 * i;
      As[h * 64 + (wl ^ (h & 31))] =
          buf1[((size_t)bc * 64 + h) * ZW + kz * 64 + wl];
    }
  }
  __syncthreads();

  // w-DFT: thread (h = tid&63, kyg = tid>>6) computes ky = kyg+4j, j=0..3
  const int h = tid & 63, kyg = tid >> 6;
  float bR[4] = {0.f, 0.f, 0.f, 0.f}, bI[4] = {0.f, 0.f, 0.f, 0.f};
  {
    const float sc = COS64[kyg];              // step = e^{-2pi i kyg/64}
    const float ss = COS64[(kyg + 48) & 63];  // sin
    float pR = 1.f, pI = 0.f;
    const int hl = h & 31;
    const float2* Ah = As + h * 64;
    for (int w1 = 0; w1 < 4; ++w1) {
#pragma unroll
      for (int w0 = 0; w0 < 16; ++w0) {
        const int w = w1 * 16 + w0;
        const float2 a = Ah[w ^ hl];
        const float tR = a.x * pR - a.y * pI;
        const float tI = a.x * pI + a.y * pR;
        bR[0] += tR; bI[0] += tI;
#pragma unroll
        for (int j = 1; j < 4; ++j) {
          const int n = (j * w0) & 15;
          const float c = C16[n], s = C16[(n + 12) & 15];
          bR[j] = fmaf(tR, c, fmaf(tI, s, bR[j]));
          bI[j] = fmaf(tI, c, fmaf(-tR, s, bI[j]));
        }
        const float nR = fmaf(pR, sc, pI * ss);
        const float nI = fmaf(pI, sc, -pR * ss);
        pR = nR; pI = nI;
      }
    }
  }
#pragma unroll
  for (int j = 0; j < 4; ++j)
    Bs[h * 17 + kyg + 4 * j] = make_float2(bR[j], bI[j]);
  __syncthreads();

  // h-DFT: thread (kx = tid>>4, ky = tid&15)
  {
    const int kx = tid >> 4, ky = tid & 15;
    const float hc = COS64[kx];               // step = e^{-2pi i kx/64}
    const float hs = COS64[(kx + 48) & 63];
    float qR = 1.f, qI = 0.f, sR = 0.f, sI = 0.f;
    for (int h2 = 0; h2 < 64; ++h2) {
      const float2 b = Bs[h2 * 17 + ky];
      sR = fmaf(b.x, qR, fmaf(-b.y, qI, sR));
      sI = fmaf(b.x, qI, fmaf( b.y, qR, sI));
      const float nR = fmaf(qR, hc, qI * hs);
      const float nI = fmaf(qI, hc, -qR * hs);
      qR = nR; qI = nI;
    }
    buf2[(size_t)bc * GD + kx * MM + ky * 9 + kz] = make_float2(sR, sI);
  }
}

// ---------------------------------------------------------------------------
// K3: gate MLP. pooled[b][c] = S_DC.re / 64^3. Writes g-1.
// ---------------------------------------------------------------------------
__global__ __launch_bounds__(256) void k3_gates(const float2* __restrict__ buf2,
    const float* __restrict__ w1, const float* __restrict__ b1,
    const float* __restrict__ w2, const float* __restrict__ b2,
    float* __restrict__ gm1) {
  __shared__ float pooled[64];
  __shared__ float hs[16];
  const int b = blockIdx.x, tid = threadIdx.x;
  if (tid < 64)
    pooled[tid] = buf2[(size_t)(b * 64 + tid) * GD].x * (1.f / 262144.f);
  __syncthreads();
  if (tid < 16) {
    float acc = b1[tid];
    for (int c = 0; c < 64; ++c) acc = fmaf(pooled[c], w1[c * 16 + tid], acc);
    hs[tid] = fmaxf(acc, 0.f);
  }
  __syncthreads();
#pragma unroll
  for (int r = 0; r < 9; ++r) {
    const int o = tid + r * 256;
    float acc = b2[o];
#pragma unroll
    for (int j = 0; j < 16; ++j) acc = fmaf(hs[j], w2[j * GD + o], acc);
    gm1[b * GD + o] = 1.f / (1.f + expf(-acc)) - 1.f;
  }
}

// ---------------------------------------------------------------------------
// K4b: inverse synthesis per slice, gate fused in phase 1; x prefetched at
//      block start so its HBM latency hides under phases 1-2.
//      out = x + delta/64^3 (plain stores: L2-merged, L3 write-back)
// ---------------------------------------------------------------------------
__global__ __launch_bounds__(256) void k4b_final(const float2* __restrict__ S,
                                                 const float* __restrict__ gm1,
                                                 const float* __restrict__ x,
                                                 float* __restrict__ out) {
  __shared__ float2 C1s[MM];
  __shared__ float2 C2s[9 * 65];       // C2[kz][w], padded
  const int tid = threadIdx.x, slice = blockIdx.x;
  const int bc = slice >> 6, h = slice & 63, b = bc >> 6;
  const int w = tid >> 2, q = tid & 3;

  // prefetch x early: 4 x float4 (64B per lane), consumed after phase 2
  const float4* xp = (const float4*)(x + ((size_t)slice << 12) + w * 64 + q * 16);
  float4 xv0 = xp[0];
  float4 xv1 = xp[1];
  float4 xv2 = xp[2];
  float4 xv3 = xp[3];

  // C1[m] = sum_kx (g-1)*S[bc][kx][m] e^{+2pi i kx h/64}
  if (tid < MM) {
    const float2* Sp = S + (size_t)bc * GD + tid;
    const float* Gp = gm1 + (size_t)b * GD + tid;
    float sn, cs;
    sincosf(TWOPI_64 * (float)h, &sn, &cs);   // step = e^{+2pi i h/64}
    float px = 1.f, py = 0.f, ar = 0.f, ai = 0.f;
#pragma unroll
    for (int kx = 0; kx < 16; ++kx) {
      const float2 sv = Sp[kx * MM];
      const float g = Gp[kx * MM];
      const float dR = sv.x * g, dI = sv.y * g;
      ar = fmaf(dR, px, fmaf(-dI, py, ar));
      ai = fmaf(dR, py, fmaf( dI, px, ai));
      const float nx = fmaf(px, cs, -py * sn);
      const float ny = fmaf(px, sn,  py * cs);
      px = nx; py = ny;
    }
    C1s[tid] = make_float2(ar, ai);
  }
  __syncthreads();

  // C2[kz][w] = sum_ky C1[ky*9+kz] e^{+2pi i ky w/64}; thread (w,q) does kz set
  {
    float sn, cs;
    sincosf(TWOPI_64 * (float)w, &sn, &cs);   // step = e^{+2pi i w/64}
    const int kz0 = q, kz1 = q + 4;           // q==0 also does kz=8
    float a0r = 0.f, a0i = 0.f, a1r = 0.f, a1i = 0.f, a2r = 0.f, a2i = 0.f;
    float px = 1.f, py = 0.f;
    for (int ky = 0; ky < 16; ++ky) {
      const float2 c0 = C1s[ky * 9 + kz0];
      const float2 c1 = C1s[ky * 9 + kz1];
      a0r = fmaf(c0.x, px, fmaf(-c0.y, py, a0r));
      a0i = fmaf(c0.x, py, fmaf( c0.y, px, a0i));
      a1r = fmaf(c1.x, px, fmaf(-c1.y, py, a1r));
      a1i = fmaf(c1.x, py, fmaf( c1.y, px, a1i));
      if (q == 0) {
        const float2 c2v = C1s[ky * 9 + 8];
        a2r = fmaf(c2v.x, px, fmaf(-c2v.y, py, a2r));
        a2i = fmaf(c2v.x, py, fmaf( c2v.y, px, a2i));
      }
      const float nx = fmaf(px, cs, -py * sn);
      const float ny = fmaf(px, sn,  py * cs);
      px = nx; py = ny;
    }
    C2s[kz0 * 65 + w] = make_float2(a0r, a0i);
    C2s[kz1 * 65 + w] = make_float2(a1r, a1i);
    if (q == 0) C2s[8 * 65 + w] = make_float2(a2r, a2i);
  }
  __syncthreads();

  // delta[w][d] = Re(C2[0]) + 2*sum_{kz>=1} Re(C2[kz] e^{+2pi i kz d/64});
  // d = 16q + j: e^{+2pi i kz d/64} = i^{kz q} * e^{+2pi i kz j/64}
  {
    float cr[9], ci[9];
#pragma unroll
    for (int kz = 0; kz < 9; ++kz) {
      const float2 v = C2s[kz * 65 + w];
      const int m = (kz * q) & 3;                 // multiply by i^m
      const float a = v.x, b2_ = v.y;
      float r  = (m & 1) ? b2_ : a;
      float i2 = (m & 1) ? a : b2_;
      r  = (m == 1 || m == 2) ? -r : r;
      i2 = (m >= 2) ? -i2 : i2;
      cr[kz] = r; ci[kz] = i2;
    }
    float acc[16];
#pragma unroll
    for (int j = 0; j < 16; ++j) acc[j] = cr[0];
#pragma unroll
    for (int kz = 1; kz < 9; ++kz) {
#pragma unroll
      for (int j = 0; j < 16; ++j) {
        const int n = (kz * j) & 63;
        acc[j] = fmaf(cr[kz],  2.f * COS64[n], acc[j]);
        acc[j] = fmaf(ci[kz], -2.f * COS64[(n + 48) & 63], acc[j]);
      }
    }
    float4* op = (float4*)(out + ((size_t)slice << 12) + w * 64 + q * 16);
    const float scale = 1.f / 262144.f;
    float4 o0 = xv0, o1 = xv1, o2 = xv2, o3 = xv3;
    o0.x += acc[0]  * scale; o0.y += acc[1]  * scale;
    o0.z += acc[2]  * scale; o0.w += acc[3]  * scale;
    o1.x += acc[4]  * scale; o1.y += acc[5]  * scale;
    o1.z += acc[6]  * scale; o1.w += acc[7]  * scale;
    o2.x += acc[8]  * scale; o2.y += acc[9]  * scale;
    o2.z += acc[10] * scale; o2.w += acc[11] * scale;
    o3.x += acc[12] * scale; o3.y += acc[13] * scale;
    o3.z += acc[14] * scale; o3.w += acc[15] * scale;
    op[0] = o0; op[1] = o1; op[2] = o2; op[3] = o3;
  }
}

} // namespace

extern "C" void kernel_launch(void* const* d_in, const int* in_sizes, int n_in,
                              void* d_out, int out_size, void* d_ws, size_t ws_size,
                              hipStream_t stream) {
  (void)in_sizes; (void)n_in; (void)out_size; (void)ws_size;
  const float* x  = (const float*)d_in[0];
  const float* w1 = (const float*)d_in[1];
  const float* b1 = (const float*)d_in[2];
  const float* w2 = (const float*)d_in[3];
  const float* b2 = (const float*)d_in[4];
  float* out = (float*)d_out;

  char* ws = (char*)d_ws;
  float2* buf1 = (float2*)ws;                          // 16384*576*8 = 75,497,472 B
  float2* buf2 = (float2*)(ws + 75497472);             // 256*2304*8  =  4,718,592 B
  float*  gm1  = (float*)(ws + 75497472 + 4718592);    // 4*2304*4    =     36,864 B

  hipLaunchKernelGGL(k1_fwd,   dim3(16384),    dim3(256), 0, stream, x, buf1);
  hipLaunchKernelGGL(k2_fwd,   dim3(9, 256),   dim3(256), 0, stream, buf1, buf2);
  hipLaunchKernelGGL(k3_gates, dim3(4),        dim3(256), 0, stream, buf2, w1, b1, w2, b2, gm1);
  hipLaunchKernelGGL(k4b_final,dim3(16384),    dim3(256), 0, stream, buf2, gm1, x, out);
}